// Round 9
// baseline (276.872 us; speedup 1.0000x reference)
//
#include <hip/hip_runtime.h>
#include <cstdint>

#define B_DIM 32
#define C_DIM 512
#define N_SP 1024
#define GROUPS 32
#define CPG 16
#define EPS 1e-5f

typedef __attribute__((ext_vector_type(8))) __bf16 bf16x8;
typedef __attribute__((ext_vector_type(4))) __bf16 bf16x4;
typedef __attribute__((ext_vector_type(4))) float f32x4;

__device__ __forceinline__ void gload16(const void* g, void* l) {
    __builtin_amdgcn_global_load_lds(
        (__attribute__((address_space(1))) void*)(unsigned long long)(uintptr_t)g,
        (__attribute__((address_space(3))) void*)(unsigned int)(uintptr_t)l,
        16, 0, 0);
}

// ------- fused GroupNorm: stats + apply + transpose, one x read -------
__global__ __launch_bounds__(256) void gn_fused_kernel(const float* __restrict__ x,
                                                       const float* __restrict__ w,
                                                       const float* __restrict__ bia,
                                                       __bf16* __restrict__ hT) {
    __shared__ float tile[16][1025];
    __shared__ float sw[16], sb[16];
    __shared__ float ls[4], lq[4];
    const int bb = blockIdx.x >> 5, g = blockIdx.x & 31;
    const int t = threadIdx.x;
    const float* xb = x + ((size_t)(bb * C_DIM + g * CPG)) * N_SP;

    float s = 0.f, sq = 0.f;
#pragma unroll
    for (int i = 0; i < 16; ++i) {
        int idx = t + 256 * i;
        int row = idx >> 8, c4 = (idx & 255) * 4;
        float4 v = *(const float4*)&xb[(size_t)row * N_SP + c4];
        tile[row][c4 + 0] = v.x; tile[row][c4 + 1] = v.y;
        tile[row][c4 + 2] = v.z; tile[row][c4 + 3] = v.w;
        s  += v.x + v.y + v.z + v.w;
        sq += v.x * v.x + v.y * v.y + v.z * v.z + v.w * v.w;
    }
    for (int off = 32; off > 0; off >>= 1) {
        s  += __shfl_xor(s, off);
        sq += __shfl_xor(sq, off);
    }
    int wid = t >> 6;
    if ((t & 63) == 0) { ls[wid] = s; lq[wid] = sq; }
    __syncthreads();
    if (t < 16) {
        s  = ls[0] + ls[1] + ls[2] + ls[3];
        sq = lq[0] + lq[1] + lq[2] + lq[3];
        float mean = s / (float)(CPG * N_SP);
        float var  = sq / (float)(CPG * N_SP) - mean * mean;
        float rstd = rsqrtf(var + EPS);
        float scl = w[g * CPG + t] * rstd;
        sw[t] = scl;
        sb[t] = bia[g * CPG + t] - mean * scl;
    }
    __syncthreads();
    __bf16* hb = hT + ((size_t)bb * N_SP) * C_DIM + g * CPG;
#pragma unroll
    for (int i = 0; i < 4; ++i) {
        int n = t + 256 * i;
        bf16x8 o1, o2;
#pragma unroll
        for (int c = 0; c < 8; ++c) o1[c] = (__bf16)(tile[c][n] * sw[c] + sb[c]);
#pragma unroll
        for (int c = 0; c < 8; ++c) o2[c] = (__bf16)(tile[8 + c][n] * sw[8 + c] + sb[8 + c]);
        *(bf16x8*)&hb[(size_t)n * C_DIM] = o1;
        *(bf16x8*)&hb[(size_t)n * C_DIM + 8] = o2;
    }
}

// ------- prep: weights fp32->bf16, pack qk bias, zero rowsum buffer -------
__global__ __launch_bounds__(256) void prep_kernel(const float* __restrict__ qw,
                                                   const float* __restrict__ kw,
                                                   const float* __restrict__ vw,
                                                   const float* __restrict__ pw,
                                                   const float* __restrict__ qb,
                                                   const float* __restrict__ kb,
                                                   __bf16* __restrict__ wqk,
                                                   __bf16* __restrict__ wv,
                                                   __bf16* __restrict__ wp,
                                                   float* __restrict__ qkb,
                                                   float* __restrict__ RS) {
    int bi = blockIdx.x;
    int t = threadIdx.x;
    if (bi >= 1025) {                       // zero RS: 32 blocks x 1024 floats
        f32x4 z = {0.f, 0.f, 0.f, 0.f};
        ((f32x4*)(RS + (size_t)(bi - 1025) * 1024))[t] = z;
        return;
    }
    if (bi == 1024) {
        int i = t * 4;
#pragma unroll
        for (int e = 0; e < 4; ++e)
            qkb[i + e] = (i + e < 512) ? qb[i + e] : kb[i + e - 512];
        return;
    }
    const float* src;
    __bf16* dst;
    int blk = bi & 255;
    if (bi < 256)       { src = qw; dst = wqk; }
    else if (bi < 512)  { src = kw; dst = wqk + 262144; }
    else if (bi < 768)  { src = vw; dst = wv; }
    else                { src = pw; dst = wp; }
    int i = blk * 256 + t;
    float4 v = ((const float4*)src)[i];
    bf16x4 o;
    o[0] = (__bf16)v.x; o[1] = (__bf16)v.y; o[2] = (__bf16)v.z; o[3] = (__bf16)v.w;
    ((bf16x4*)dst)[i] = o;
}

// ============ 128x128 8-wave GEMM, BK=64, dbuf, depth-1.5 prefetch ============
// EPI: 2 bf16+bias[row]; 4 f32+bias[row]+resid (x prefetched in tail tile);
//      6 bf16+bias[col] split q/k; 8 scores: exp(acc*scale)->bf16 + row-sum atomics;
//      9 AV: bf16 acc * (1/RS[row])
#define WAITV(n) asm volatile("s_waitcnt vmcnt(" #n ")" ::: "memory")
#define BAR() __builtin_amdgcn_s_barrier()

template <int M, int N, int K, int LDA, int LDB, int EPI>
__global__ __launch_bounds__(512, 4) void gemmP(const __bf16* __restrict__ A, size_t sA,
                                                const __bf16* __restrict__ BT, size_t sB,
                                                void* __restrict__ Y, size_t sY,
                                                const float* __restrict__ bias,
                                                const float* __restrict__ resid, size_t sR,
                                                float scale, void* __restrict__ Y2,
                                                float* __restrict__ RS) {
    static_assert(M % 128 == 0 && N % 128 == 0 && K % 128 == 0, "shape");
    constexpr int GX = N / 128, GY = M / 128, NT = K / 64;
    __shared__ __align__(16) __bf16 lds[2][2][8192];   // [buf][A/B][128 rows x 64 k]

    const int tid = threadIdx.x;
    const int w = tid >> 6, lane = tid & 63;
    const int wm = w >> 1, wn = w & 1;                 // 4 x 2 wave grid, tile 32x64
    const int lrow = lane & 15, koct = lane >> 4;

    const int nwg = gridDim.x;
    const int wg = ((int)blockIdx.x & 7) * (nwg >> 3) + ((int)blockIdx.x >> 3);
    const int bz = wg / (GX * GY);
    const int rem = wg - bz * (GX * GY);
    const int bm = (rem / GX) * 128, bn = (rem % GX) * 128;

    const __bf16* Ab = A + (size_t)bz * sA;
    const __bf16* Bb = BT + (size_t)bz * sB;

    const int srow = tid >> 3;
    const int kswz = ((tid & 7) ^ (srow & 7)) * 8;
    const __bf16* srcA = Ab + (size_t)(bm + srow) * LDA + kswz;
    const __bf16* srcB = Bb + (size_t)(bn + srow) * LDB + kswz;

#define STG(buf, kt) do { \
    gload16(srcA + (size_t)(kt) * 64,                      &lds[buf][0][w * 512]); \
    gload16(srcA + (size_t)64 * LDA + (size_t)(kt) * 64,   &lds[buf][0][4096 + w * 512]); \
    gload16(srcB + (size_t)(kt) * 64,                      &lds[buf][1][w * 512]); \
    gload16(srcB + (size_t)64 * LDB + (size_t)(kt) * 64,   &lds[buf][1][4096 + w * 512]); \
} while (0)

    const int ks0 = (koct ^ (lrow & 7)) * 8;
    const int ks1 = ks0 ^ 32;
    const int aoff = (wm * 32 + lrow) * 64;
    const int boff = (wn * 64 + lrow) * 64;

    bf16x8 aF[2][2], bF[4][2];
    f32x4 acc[2][4];
#pragma unroll
    for (int i = 0; i < 2; ++i)
#pragma unroll
        for (int j = 0; j < 4; ++j) acc[i][j] = (f32x4){0.f, 0.f, 0.f, 0.f};

    const float* Rb = (EPI == 4) ? (resid + (size_t)bz * sR) : nullptr;
    float xr[2][4][4];   // EPI==4 residual prefetch (DCE'd otherwise)

#define RD_ALL(ct) do { \
    _Pragma("unroll") for (int i = 0; i < 2; ++i) { \
        aF[i][0] = *(const bf16x8*)&lds[ct][0][aoff + i * 1024 + ks0]; \
        aF[i][1] = *(const bf16x8*)&lds[ct][0][aoff + i * 1024 + ks1]; } \
    _Pragma("unroll") for (int j = 0; j < 4; ++j) { \
        bF[j][0] = *(const bf16x8*)&lds[ct][1][boff + j * 1024 + ks0]; \
        bF[j][1] = *(const bf16x8*)&lds[ct][1][boff + j * 1024 + ks1]; } \
} while (0)

#define MM8(KS) do { \
    __builtin_amdgcn_s_setprio(1); \
    _Pragma("unroll") for (int i = 0; i < 2; ++i) \
    _Pragma("unroll") for (int j = 0; j < 4; ++j) \
        acc[i][j] = __builtin_amdgcn_mfma_f32_16x16x32_bf16( \
            aF[i][KS], bF[j][KS], acc[i][j], 0, 0, 0); \
    __builtin_amdgcn_s_setprio(0); \
} while (0)

    STG(0, 0);
    STG(1, 1);

#pragma unroll 1
    for (int t = 0; t < NT; ++t) {
        const int c = t & 1;
        if (t < NT - 1) { WAITV(4); } else { WAITV(0); }
        BAR();
        if constexpr (EPI == 4) {
            if (t == NT - 1) {     // residual prefetch flies under tail MFMAs
#pragma unroll
                for (int i = 0; i < 2; ++i)
#pragma unroll
                    for (int r = 0; r < 4; ++r)
#pragma unroll
                        for (int j = 0; j < 4; ++j)
                            xr[i][r][j] = Rb[(size_t)(bm + wm * 32 + i * 16 + koct * 4 + r) * N
                                             + bn + wn * 64 + j * 16 + lrow];
            }
        }
        RD_ALL(c);
        MM8(0);
        asm volatile("s_waitcnt lgkmcnt(0)" ::: "memory");
        __builtin_amdgcn_sched_barrier(0);
        BAR();
        if (t + 2 < NT) STG(c, t + 2);
        MM8(1);
    }

    // epilogue: C/D layout col=lane&15, row=koct*4+reg
    float* Yf = (float*)Y + (size_t)bz * sY;
    __bf16* Yh = (__bf16*)Y + (size_t)bz * sY;
    __bf16* Y6 = (EPI == 6) ? ((bn < 512) ? (__bf16*)Y : (__bf16*)Y2) : nullptr;

    if constexpr (EPI == 8) {
        // p = exp(min(acc*scale,50)); write bf16 P; accumulate row sums
#pragma unroll
        for (int i = 0; i < 2; ++i)
#pragma unroll
            for (int r = 0; r < 4; ++r) {
                int grow = bm + wm * 32 + i * 16 + koct * 4 + r;
                float p[4];
                float rsum = 0.f;
#pragma unroll
                for (int j = 0; j < 4; ++j) {
                    p[j] = __expf(fminf(acc[i][j][r] * scale, 50.f));
                    rsum += p[j];
                }
                rsum += __shfl_xor(rsum, 1);
                rsum += __shfl_xor(rsum, 2);
                rsum += __shfl_xor(rsum, 4);
                rsum += __shfl_xor(rsum, 8);
                if (lrow == 0) atomicAdd(&RS[(size_t)bz * 1024 + grow], rsum);
#pragma unroll
                for (int j = 0; j < 4; ++j)
                    Yh[(size_t)grow * N + bn + wn * 64 + j * 16 + lrow] = (__bf16)p[j];
            }
    } else if constexpr (EPI == 9) {
#pragma unroll
        for (int i = 0; i < 2; ++i)
#pragma unroll
            for (int r = 0; r < 4; ++r) {
                int grow = bm + wm * 32 + i * 16 + koct * 4 + r;
                float rs = 1.0f / RS[(size_t)bz * 1024 + grow];
#pragma unroll
                for (int j = 0; j < 4; ++j)
                    Yh[(size_t)grow * N + bn + wn * 64 + j * 16 + lrow]
                        = (__bf16)(acc[i][j][r] * rs);
            }
    } else {
#pragma unroll
        for (int i = 0; i < 2; ++i)
#pragma unroll
            for (int r = 0; r < 4; ++r) {
                int grow = bm + wm * 32 + i * 16 + koct * 4 + r;
                float brv = (EPI == 2 || EPI == 4) ? bias[grow] : 0.f;
#pragma unroll
                for (int j = 0; j < 4; ++j) {
                    int gcol = bn + wn * 64 + j * 16 + lrow;
                    float vv = acc[i][j][r];
                    if (EPI == 6) vv += bias[gcol];
                    if (EPI == 2 || EPI == 4) vv += brv;
                    if (EPI == 4) {
                        Yf[(size_t)grow * N + gcol] = vv + xr[i][r][j & 3];
                    } else if (EPI == 6) {
                        Y6[(size_t)grow * 512 + (gcol & 511)] = (__bf16)vv;
                    } else {
                        Yh[(size_t)grow * N + gcol] = (__bf16)vv;
                    }
                }
            }
    }
#undef STG
#undef RD_ALL
#undef MM8
}

extern "C" void kernel_launch(void* const* d_in, const int* in_sizes, int n_in,
                              void* d_out, int out_size, void* d_ws, size_t ws_size,
                              hipStream_t stream) {
    const float* x      = (const float*)d_in[0];
    const float* norm_w = (const float*)d_in[1];
    const float* norm_b = (const float*)d_in[2];
    const float* q_w    = (const float*)d_in[3];
    const float* q_b    = (const float*)d_in[4];
    const float* k_w    = (const float*)d_in[5];
    const float* k_b    = (const float*)d_in[6];
    const float* v_w    = (const float*)d_in[7];
    const float* v_b    = (const float*)d_in[8];
    const float* proj_w = (const float*)d_in[9];
    const float* proj_b = (const float*)d_in[10];
    float* out = (float*)d_out;

    const size_t ELEM = (size_t)N_SP * C_DIM;            // 524288 elems = 1MB bf16
    const size_t QK   = (size_t)N_SP * N_SP;
    char* ws = (char*)d_ws;
    __bf16* hT  = (__bf16*)ws;                           // 32MB [b][n][c], reused as Ot
    __bf16* qT  = (__bf16*)(ws + ((size_t)32 << 20));    // 32MB [b][n][512]
    __bf16* kT  = (__bf16*)(ws + ((size_t)64 << 20));    // 32MB [b][n][512]
    __bf16* wqk = (__bf16*)(ws + ((size_t)96 << 20));    // 1MB [1024][512]
    __bf16* wv  = (__bf16*)(ws + ((size_t)97 << 20));    // 0.5MB
    __bf16* wp  = wv + 262144;                           // 0.5MB
    float* qkb  = (float*)(ws + ((size_t)98 << 20));     // 4KB
    float* RS   = (float*)(ws + ((size_t)98 << 20) + 65536);   // 128KB rowsums
    size_t sbase = ((size_t)99 << 20);
    __bf16* S = (__bf16*)(ws + sbase);                   // chunk x [1024][1024] bf16
    __bf16* v  = (__bf16*)d_out;                         // V lives in d_out until proj
    __bf16* Ot = hT;

    int chunk = (int)((ws_size - sbase) >> 21);          // 2MB per batch of S
    if (chunk > B_DIM) chunk = B_DIM;
    if (chunk < 1) chunk = 1;

    gn_fused_kernel<<<B_DIM * GROUPS, 256, 0, stream>>>(x, norm_w, norm_b, hT);
    prep_kernel<<<1057, 256, 0, stream>>>(q_w, k_w, v_w, proj_w, q_b, k_b,
                                          wqk, wv, wp, qkb, RS);

    // qT[n][oc] / kT[n][oc] = hT[n][:] x (wq||wk)^T + bias, split outputs
    gemmP<32768, 1024, 512, 512, 512, 6><<<2048, 512, 0, stream>>>(
        hT, 0, wqk, 0, qT, 0, qkb, nullptr, 0, 1.f, kT, nullptr);
    // v[b][oc][n] = wv[oc][:] x hT[b][n][:] + v_b[oc]
    gemmP<512, 1024, 512, 512, 512, 2><<<1024, 512, 0, stream>>>(
        wv, 0, hT, ELEM, v, ELEM, v_b, nullptr, 0, 1.f, nullptr, nullptr);

    const float scale = 0.044194173824159216f;  // 512^-0.5
    for (int b0 = 0; b0 < B_DIM; b0 += chunk) {
        int nb = (b0 + chunk <= B_DIM) ? chunk : (B_DIM - b0);
        // S[i][j] = exp(scale * q.k)  (bf16, unnormalized) + row sums into RS
        gemmP<1024, 1024, 512, 512, 512, 8><<<64 * nb, 512, 0, stream>>>(
            qT + (size_t)b0 * ELEM, ELEM, kT + (size_t)b0 * ELEM, ELEM,
            S, QK, nullptr, nullptr, 0, scale, nullptr, RS + (size_t)b0 * 1024);
        // Ot[i][c] = (sum_j P[i][j] v[c][j]) / RS[i]
        gemmP<1024, 512, 1024, 1024, 1024, 9><<<32 * nb, 512, 0, stream>>>(
            S, QK, v + (size_t)b0 * ELEM, ELEM,
            Ot + (size_t)b0 * ELEM, ELEM, nullptr, nullptr, 0, 1.f, nullptr,
            RS + (size_t)b0 * 1024);
    }

    // out[b][oc][n] = wp[oc][:] x Ot[b][n][:] + proj_b[oc] + x[b][oc][n]
    gemmP<512, 1024, 512, 512, 512, 4><<<1024, 512, 0, stream>>>(
        wp, 0, Ot, ELEM, out, ELEM, proj_b, x, ELEM, 1.f, nullptr, nullptr);
}

// Round 10
// 253.719 us; speedup vs baseline: 1.0913x; 1.0913x over previous
//
#include <hip/hip_runtime.h>
#include <cstdint>

#define B_DIM 32
#define C_DIM 512
#define N_SP 1024
#define GROUPS 32
#define CPG 16
#define EPS 1e-5f

typedef __attribute__((ext_vector_type(8))) __bf16 bf16x8;
typedef __attribute__((ext_vector_type(4))) __bf16 bf16x4;
typedef __attribute__((ext_vector_type(4))) float f32x4;

__device__ __forceinline__ void gload16(const void* g, void* l) {
    __builtin_amdgcn_global_load_lds(
        (__attribute__((address_space(1))) void*)(unsigned long long)(uintptr_t)g,
        (__attribute__((address_space(3))) void*)(unsigned int)(uintptr_t)l,
        16, 0, 0);
}

// ------- fused GroupNorm: stats + apply + transpose, one x read -------
__global__ __launch_bounds__(256) void gn_fused_kernel(const float* __restrict__ x,
                                                       const float* __restrict__ w,
                                                       const float* __restrict__ bia,
                                                       __bf16* __restrict__ hT) {
    __shared__ float tile[16][1025];
    __shared__ float sw[16], sb[16];
    __shared__ float ls[4], lq[4];
    const int bb = blockIdx.x >> 5, g = blockIdx.x & 31;
    const int t = threadIdx.x;
    const float* xb = x + ((size_t)(bb * C_DIM + g * CPG)) * N_SP;

    float s = 0.f, sq = 0.f;
#pragma unroll
    for (int i = 0; i < 16; ++i) {
        int idx = t + 256 * i;
        int row = idx >> 8, c4 = (idx & 255) * 4;
        float4 v = *(const float4*)&xb[(size_t)row * N_SP + c4];
        tile[row][c4 + 0] = v.x; tile[row][c4 + 1] = v.y;
        tile[row][c4 + 2] = v.z; tile[row][c4 + 3] = v.w;
        s  += v.x + v.y + v.z + v.w;
        sq += v.x * v.x + v.y * v.y + v.z * v.z + v.w * v.w;
    }
    for (int off = 32; off > 0; off >>= 1) {
        s  += __shfl_xor(s, off);
        sq += __shfl_xor(sq, off);
    }
    int wid = t >> 6;
    if ((t & 63) == 0) { ls[wid] = s; lq[wid] = sq; }
    __syncthreads();
    if (t < 16) {
        s  = ls[0] + ls[1] + ls[2] + ls[3];
        sq = lq[0] + lq[1] + lq[2] + lq[3];
        float mean = s / (float)(CPG * N_SP);
        float var  = sq / (float)(CPG * N_SP) - mean * mean;
        float rstd = rsqrtf(var + EPS);
        float scl = w[g * CPG + t] * rstd;
        sw[t] = scl;
        sb[t] = bia[g * CPG + t] - mean * scl;
    }
    __syncthreads();
    __bf16* hb = hT + ((size_t)bb * N_SP) * C_DIM + g * CPG;
#pragma unroll
    for (int i = 0; i < 4; ++i) {
        int n = t + 256 * i;
        bf16x8 o1, o2;
#pragma unroll
        for (int c = 0; c < 8; ++c) o1[c] = (__bf16)(tile[c][n] * sw[c] + sb[c]);
#pragma unroll
        for (int c = 0; c < 8; ++c) o2[c] = (__bf16)(tile[8 + c][n] * sw[8 + c] + sb[8 + c]);
        *(bf16x8*)&hb[(size_t)n * C_DIM] = o1;
        *(bf16x8*)&hb[(size_t)n * C_DIM + 8] = o2;
    }
}

// ------- prep: weights fp32->bf16 + pack qk bias -------
__global__ __launch_bounds__(256) void prep_kernel(const float* __restrict__ qw,
                                                   const float* __restrict__ kw,
                                                   const float* __restrict__ vw,
                                                   const float* __restrict__ pw,
                                                   const float* __restrict__ qb,
                                                   const float* __restrict__ kb,
                                                   __bf16* __restrict__ wqk,
                                                   __bf16* __restrict__ wv,
                                                   __bf16* __restrict__ wp,
                                                   float* __restrict__ qkb) {
    int bi = blockIdx.x;
    int t = threadIdx.x;
    if (bi == 1024) {
        int i = t * 4;
#pragma unroll
        for (int e = 0; e < 4; ++e)
            qkb[i + e] = (i + e < 512) ? qb[i + e] : kb[i + e - 512];
        return;
    }
    const float* src;
    __bf16* dst;
    int blk = bi & 255;
    if (bi < 256)       { src = qw; dst = wqk; }
    else if (bi < 512)  { src = kw; dst = wqk + 262144; }
    else if (bi < 768)  { src = vw; dst = wv; }
    else                { src = pw; dst = wp; }
    int i = blk * 256 + t;
    float4 v = ((const float4*)src)[i];
    bf16x4 o;
    o[0] = (__bf16)v.x; o[1] = (__bf16)v.y; o[2] = (__bf16)v.z; o[3] = (__bf16)v.w;
    ((bf16x4*)dst)[i] = o;
}

// ------- softmax: one wave per row of 1024 bf16, in place, no LDS -------
__global__ __launch_bounds__(256) void softmax_bf16(__bf16* __restrict__ S) {
    int row = blockIdx.x * 4 + (threadIdx.x >> 6);
    int lane = threadIdx.x & 63;
    __bf16* p = S + (size_t)row * N_SP + lane * 16;
    bf16x8 v0 = *(bf16x8*)p;
    bf16x8 v1 = *(bf16x8*)(p + 8);
    float f[16];
#pragma unroll
    for (int e = 0; e < 8; ++e) { f[e] = (float)v0[e]; f[8 + e] = (float)v1[e]; }
    float m = f[0];
#pragma unroll
    for (int e = 1; e < 16; ++e) m = fmaxf(m, f[e]);
    for (int off = 32; off > 0; off >>= 1) m = fmaxf(m, __shfl_xor(m, off));
    float s = 0.f;
#pragma unroll
    for (int e = 0; e < 16; ++e) { f[e] = __expf(f[e] - m); s += f[e]; }
    for (int off = 32; off > 0; off >>= 1) s += __shfl_xor(s, off);
    float inv = 1.f / s;
#pragma unroll
    for (int e = 0; e < 8; ++e) { v0[e] = (__bf16)(f[e] * inv); v1[e] = (__bf16)(f[8 + e] * inv); }
    *(bf16x8*)p = v0;
    *(bf16x8*)(p + 8) = v1;
}

// ======== 128x128 GEMM, 4 waves x 64x64 wave-tile, BK=64, dbuf, 2 blocks/CU ========
// LDS-read-BW optimized: 16 ds_read_b128 per 32 MFMA per wave (0.5 r/M vs 0.75 prior).
// Schedule per tile t (buf c): WAITV(8) -> BAR -> 16 reads -> MFMA(ks0) ->
// lgkmcnt(0) -> BAR -> STG(c, t+2) (8 gloads) -> MFMA(ks1). Counted vmcnt only.
// EPI: 0 bf16; 2 bf16+bias[row]; 4 f32+bias[row]+resid (resid prefetched in tail);
//      5 bf16*scale; 6 bf16+bias[col] split cols<512 -> Y, >=512 -> Y2
#define WAITV(n) asm volatile("s_waitcnt vmcnt(" #n ")" ::: "memory")
#define BAR() __builtin_amdgcn_s_barrier()

template <int M, int N, int K, int LDA, int LDB, int EPI>
__global__ __launch_bounds__(256, 2) void gemmW(const __bf16* __restrict__ A, size_t sA,
                                                const __bf16* __restrict__ BT, size_t sB,
                                                void* __restrict__ Y, size_t sY,
                                                const float* __restrict__ bias,
                                                const float* __restrict__ resid, size_t sR,
                                                float scale, void* __restrict__ Y2) {
    static_assert(M % 128 == 0 && N % 128 == 0 && K % 192 != 0 && K % 64 == 0, "shape");
    constexpr int GX = N / 128, GY = M / 128, NT = K / 64;
    __shared__ __align__(16) __bf16 lds[2][2][8192];   // [buf][A/B][128 rows x 64 k]

    const int tid = threadIdx.x;
    const int w = tid >> 6, lane = tid & 63;
    const int wm = w >> 1, wn = w & 1;                 // 2 x 2 wave grid, tile 64x64
    const int lrow = lane & 15, koct = lane >> 4;

    const int nwg = gridDim.x;
    const int wg = ((int)blockIdx.x & 7) * (nwg >> 3) + ((int)blockIdx.x >> 3);
    const int bz = wg / (GX * GY);
    const int rem = wg - bz * (GX * GY);
    const int bm = (rem / GX) * 128, bn = (rem % GX) * 128;

    const __bf16* Ab = A + (size_t)bz * sA;
    const __bf16* Bb = BT + (size_t)bz * sB;

    // staging: 256 thr cover 32 rows/call (8 calls per K-tile); source k pre-swizzled
    const int srow = tid >> 3;                          // 0..31
    const int kswz = ((tid & 7) ^ (srow & 7)) * 8;
    const __bf16* srcA = Ab + (size_t)(bm + srow) * LDA + kswz;
    const __bf16* srcB = Bb + (size_t)(bn + srow) * LDB + kswz;

#define STG(buf, kt) do { \
    gload16(srcA + (size_t)(kt) * 64,                     &lds[buf][0][w * 512]); \
    gload16(srcA + (size_t)32 * LDA + (size_t)(kt) * 64,  &lds[buf][0][2048 + w * 512]); \
    gload16(srcA + (size_t)64 * LDA + (size_t)(kt) * 64,  &lds[buf][0][4096 + w * 512]); \
    gload16(srcA + (size_t)96 * LDA + (size_t)(kt) * 64,  &lds[buf][0][6144 + w * 512]); \
    gload16(srcB + (size_t)(kt) * 64,                     &lds[buf][1][w * 512]); \
    gload16(srcB + (size_t)32 * LDB + (size_t)(kt) * 64,  &lds[buf][1][2048 + w * 512]); \
    gload16(srcB + (size_t)64 * LDB + (size_t)(kt) * 64,  &lds[buf][1][4096 + w * 512]); \
    gload16(srcB + (size_t)96 * LDB + (size_t)(kt) * 64,  &lds[buf][1][6144 + w * 512]); \
} while (0)

    // fragment reads (read side of the swizzle involution)
    const int ks0 = (koct ^ (lrow & 7)) * 8;
    const int ks1 = ks0 ^ 32;
    const int aoff = (wm * 64 + lrow) * 64;
    const int boff = (wn * 64 + lrow) * 64;

    bf16x8 aF[4][2], bF[4][2];
    f32x4 acc[4][4];
#pragma unroll
    for (int i = 0; i < 4; ++i)
#pragma unroll
        for (int j = 0; j < 4; ++j) acc[i][j] = (f32x4){0.f, 0.f, 0.f, 0.f};

    const float* Rb = (EPI == 4) ? (resid + (size_t)bz * sR) : nullptr;
    float xr[4][4][4];   // EPI==4 residual prefetch (DCE'd otherwise)

#define RD_ALL(ct) do { \
    _Pragma("unroll") for (int i = 0; i < 4; ++i) { \
        aF[i][0] = *(const bf16x8*)&lds[ct][0][aoff + i * 1024 + ks0]; \
        aF[i][1] = *(const bf16x8*)&lds[ct][0][aoff + i * 1024 + ks1]; } \
    _Pragma("unroll") for (int j = 0; j < 4; ++j) { \
        bF[j][0] = *(const bf16x8*)&lds[ct][1][boff + j * 1024 + ks0]; \
        bF[j][1] = *(const bf16x8*)&lds[ct][1][boff + j * 1024 + ks1]; } \
} while (0)

#define MM16(KS) do { \
    __builtin_amdgcn_s_setprio(1); \
    _Pragma("unroll") for (int i = 0; i < 4; ++i) \
    _Pragma("unroll") for (int j = 0; j < 4; ++j) \
        acc[i][j] = __builtin_amdgcn_mfma_f32_16x16x32_bf16( \
            aF[i][KS], bF[j][KS], acc[i][j], 0, 0, 0); \
    __builtin_amdgcn_s_setprio(0); \
} while (0)

    // prologue: stage tiles 0 and 1 (16 gloads in flight)
    STG(0, 0);
    STG(1, 1);

#pragma unroll 1
    for (int t = 0; t < NT; ++t) {
        const int c = t & 1;
        if (t < NT - 1) { WAITV(8); } else { WAITV(0); }
        BAR();
        if constexpr (EPI == 4) {
            if (t == NT - 1) {     // residual prefetch flies under tail MFMAs
#pragma unroll
                for (int i = 0; i < 4; ++i)
#pragma unroll
                    for (int r = 0; r < 4; ++r)
#pragma unroll
                        for (int j = 0; j < 4; ++j)
                            xr[i][r][j] = Rb[(size_t)(bm + wm * 64 + i * 16 + koct * 4 + r) * N
                                             + bn + wn * 64 + j * 16 + lrow];
            }
        }
        RD_ALL(c);                 // 16 x ds_read_b128
        MM16(0);
        asm volatile("s_waitcnt lgkmcnt(0)" ::: "memory");
        __builtin_amdgcn_sched_barrier(0);
        BAR();                     // all waves done reading buf c
        if (t + 2 < NT) STG(c, t + 2);
        MM16(1);
    }

    // epilogue: C/D layout col=lane&15, row=koct*4+reg
    float* Yf = (float*)Y + (size_t)bz * sY;
    __bf16* Yh = (__bf16*)Y + (size_t)bz * sY;
    __bf16* Y6 = (EPI == 6) ? ((bn < 512) ? (__bf16*)Y : (__bf16*)Y2) : nullptr;
#pragma unroll
    for (int i = 0; i < 4; ++i)
#pragma unroll
        for (int r = 0; r < 4; ++r) {
            int grow = bm + wm * 64 + i * 16 + koct * 4 + r;
            float brv = (EPI == 2 || EPI == 4) ? bias[grow] : 0.f;
#pragma unroll
            for (int j = 0; j < 4; ++j) {
                int gcol = bn + wn * 64 + j * 16 + lrow;
                float vv = acc[i][j][r];
                if (EPI == 6) vv += bias[gcol];
                if (EPI == 2 || EPI == 4) vv += brv;
                if (EPI == 5) vv *= scale;
                if (EPI == 4) {
                    Yf[(size_t)grow * N + gcol] = vv + xr[i][r][j];
                } else if (EPI == 6) {
                    Y6[(size_t)grow * 512 + (gcol & 511)] = (__bf16)vv;
                } else {
                    Yh[(size_t)grow * N + gcol] = (__bf16)vv;
                }
            }
        }
#undef STG
#undef RD_ALL
#undef MM16
}

extern "C" void kernel_launch(void* const* d_in, const int* in_sizes, int n_in,
                              void* d_out, int out_size, void* d_ws, size_t ws_size,
                              hipStream_t stream) {
    const float* x      = (const float*)d_in[0];
    const float* norm_w = (const float*)d_in[1];
    const float* norm_b = (const float*)d_in[2];
    const float* q_w    = (const float*)d_in[3];
    const float* q_b    = (const float*)d_in[4];
    const float* k_w    = (const float*)d_in[5];
    const float* k_b    = (const float*)d_in[6];
    const float* v_w    = (const float*)d_in[7];
    const float* v_b    = (const float*)d_in[8];
    const float* proj_w = (const float*)d_in[9];
    const float* proj_b = (const float*)d_in[10];
    float* out = (float*)d_out;

    const size_t ELEM = (size_t)N_SP * C_DIM;            // 524288 elems = 1MB bf16
    const size_t QK   = (size_t)N_SP * N_SP;
    char* ws = (char*)d_ws;
    __bf16* hT  = (__bf16*)ws;                           // 32MB [b][n][c], reused as Ot
    __bf16* qT  = (__bf16*)(ws + ((size_t)32 << 20));    // 32MB [b][n][512]
    __bf16* kT  = (__bf16*)(ws + ((size_t)64 << 20));    // 32MB [b][n][512]
    __bf16* wqk = (__bf16*)(ws + ((size_t)96 << 20));    // 1MB [1024][512]
    __bf16* wv  = (__bf16*)(ws + ((size_t)97 << 20));    // 0.5MB
    __bf16* wp  = wv + 262144;                           // 0.5MB
    float* qkb  = (float*)(ws + ((size_t)98 << 20));     // 4KB
    size_t sbase = ((size_t)99 << 20);
    __bf16* S = (__bf16*)(ws + sbase);                   // chunk x [1024][1024] bf16
    __bf16* v  = (__bf16*)d_out;                         // V lives in d_out until proj
    __bf16* Ot = hT;

    int chunk = (int)((ws_size - sbase) >> 21);          // 2MB per batch of S
    if (chunk > B_DIM) chunk = B_DIM;
    if (chunk < 1) chunk = 1;

    gn_fused_kernel<<<B_DIM * GROUPS, 256, 0, stream>>>(x, norm_w, norm_b, hT);
    prep_kernel<<<1025, 256, 0, stream>>>(q_w, k_w, v_w, proj_w, q_b, k_b,
                                          wqk, wv, wp, qkb);

    // qT[n][oc] / kT[n][oc] = hT[n][:] x (wq||wk)^T + bias, split outputs
    gemmW<32768, 1024, 512, 512, 512, 6><<<2048, 256, 0, stream>>>(
        hT, 0, wqk, 0, qT, 0, qkb, nullptr, 0, 1.f, kT);
    // v[b][oc][n] = wv[oc][:] x hT[b][n][:] + v_b[oc]
    gemmW<512, 1024, 512, 512, 512, 2><<<1024, 256, 0, stream>>>(
        wv, 0, hT, ELEM, v, ELEM, v_b, nullptr, 0, 1.f, nullptr);

    const float scale = 0.044194173824159216f;  // 512^-0.5
    for (int b0 = 0; b0 < B_DIM; b0 += chunk) {
        int nb = (b0 + chunk <= B_DIM) ? chunk : (B_DIM - b0);
        // S[i][j] = bf16( scale * sum_c qT[i][c] kT[j][c] )
        gemmW<1024, 1024, 512, 512, 512, 5><<<64 * nb, 256, 0, stream>>>(
            qT + (size_t)b0 * ELEM, ELEM, kT + (size_t)b0 * ELEM, ELEM,
            S, QK, nullptr, nullptr, 0, scale, nullptr);
        softmax_bf16<<<nb * N_SP / 4, 256, 0, stream>>>(S);
        // Ot[i][c] = sum_j P[i][j] v[c][j]
        gemmW<1024, 512, 1024, 1024, 1024, 0><<<32 * nb, 256, 0, stream>>>(
            S, QK, v + (size_t)b0 * ELEM, ELEM,
            Ot + (size_t)b0 * ELEM, ELEM, nullptr, nullptr, 0, 1.f, nullptr);
    }

    // out[b][oc][n] = wp[oc][:] x Ot[b][n][:] + proj_b[oc] + x[b][oc][n]
    gemmW<512, 1024, 512, 512, 512, 4><<<1024, 256, 0, stream>>>(
        wp, 0, Ot, ELEM, out, ELEM, proj_b, x, ELEM, 1.f, nullptr);
}

// Round 11
// 250.931 us; speedup vs baseline: 1.1034x; 1.0111x over previous
//
#include <hip/hip_runtime.h>
#include <cstdint>

#define B_DIM 32
#define C_DIM 512
#define N_SP 1024
#define GROUPS 32
#define CPG 16
#define EPS 1e-5f

typedef __attribute__((ext_vector_type(8))) __bf16 bf16x8;
typedef __attribute__((ext_vector_type(4))) __bf16 bf16x4;
typedef __attribute__((ext_vector_type(4))) float f32x4;

__device__ __forceinline__ void gload16(const void* g, void* l) {
    __builtin_amdgcn_global_load_lds(
        (__attribute__((address_space(1))) void*)(unsigned long long)(uintptr_t)g,
        (__attribute__((address_space(3))) void*)(unsigned int)(uintptr_t)l,
        16, 0, 0);
}

// ------- fused GroupNorm: stats + apply + transpose, one x read -------
__global__ __launch_bounds__(256) void gn_fused_kernel(const float* __restrict__ x,
                                                       const float* __restrict__ w,
                                                       const float* __restrict__ bia,
                                                       __bf16* __restrict__ hT) {
    __shared__ float tile[16][1025];
    __shared__ float sw[16], sb[16];
    __shared__ float ls[4], lq[4];
    const int bb = blockIdx.x >> 5, g = blockIdx.x & 31;
    const int t = threadIdx.x;
    const float* xb = x + ((size_t)(bb * C_DIM + g * CPG)) * N_SP;

    float s = 0.f, sq = 0.f;
#pragma unroll
    for (int i = 0; i < 16; ++i) {
        int idx = t + 256 * i;
        int row = idx >> 8, c4 = (idx & 255) * 4;
        float4 v = *(const float4*)&xb[(size_t)row * N_SP + c4];
        tile[row][c4 + 0] = v.x; tile[row][c4 + 1] = v.y;
        tile[row][c4 + 2] = v.z; tile[row][c4 + 3] = v.w;
        s  += v.x + v.y + v.z + v.w;
        sq += v.x * v.x + v.y * v.y + v.z * v.z + v.w * v.w;
    }
    for (int off = 32; off > 0; off >>= 1) {
        s  += __shfl_xor(s, off);
        sq += __shfl_xor(sq, off);
    }
    int wid = t >> 6;
    if ((t & 63) == 0) { ls[wid] = s; lq[wid] = sq; }
    __syncthreads();
    if (t < 16) {
        s  = ls[0] + ls[1] + ls[2] + ls[3];
        sq = lq[0] + lq[1] + lq[2] + lq[3];
        float mean = s / (float)(CPG * N_SP);
        float var  = sq / (float)(CPG * N_SP) - mean * mean;
        float rstd = rsqrtf(var + EPS);
        float scl = w[g * CPG + t] * rstd;
        sw[t] = scl;
        sb[t] = bia[g * CPG + t] - mean * scl;
    }
    __syncthreads();
    __bf16* hb = hT + ((size_t)bb * N_SP) * C_DIM + g * CPG;
#pragma unroll
    for (int i = 0; i < 4; ++i) {
        int n = t + 256 * i;
        bf16x8 o1, o2;
#pragma unroll
        for (int c = 0; c < 8; ++c) o1[c] = (__bf16)(tile[c][n] * sw[c] + sb[c]);
#pragma unroll
        for (int c = 0; c < 8; ++c) o2[c] = (__bf16)(tile[8 + c][n] * sw[8 + c] + sb[8 + c]);
        *(bf16x8*)&hb[(size_t)n * C_DIM] = o1;
        *(bf16x8*)&hb[(size_t)n * C_DIM + 8] = o2;
    }
}

// ------- prep: weights fp32->bf16 + pack qk bias -------
__global__ __launch_bounds__(256) void prep_kernel(const float* __restrict__ qw,
                                                   const float* __restrict__ kw,
                                                   const float* __restrict__ vw,
                                                   const float* __restrict__ pw,
                                                   const float* __restrict__ qb,
                                                   const float* __restrict__ kb,
                                                   __bf16* __restrict__ wqk,
                                                   __bf16* __restrict__ wv,
                                                   __bf16* __restrict__ wp,
                                                   float* __restrict__ qkb) {
    int bi = blockIdx.x;
    int t = threadIdx.x;
    if (bi == 1024) {
        int i = t * 4;
#pragma unroll
        for (int e = 0; e < 4; ++e)
            qkb[i + e] = (i + e < 512) ? qb[i + e] : kb[i + e - 512];
        return;
    }
    const float* src;
    __bf16* dst;
    int blk = bi & 255;
    if (bi < 256)       { src = qw; dst = wqk; }
    else if (bi < 512)  { src = kw; dst = wqk + 262144; }
    else if (bi < 768)  { src = vw; dst = wv; }
    else                { src = pw; dst = wp; }
    int i = blk * 256 + t;
    float4 v = ((const float4*)src)[i];
    bf16x4 o;
    o[0] = (__bf16)v.x; o[1] = (__bf16)v.y; o[2] = (__bf16)v.z; o[3] = (__bf16)v.w;
    ((bf16x4*)dst)[i] = o;
}

// ------- softmax: one wave per row of 1024 bf16, in place, no LDS -------
__global__ __launch_bounds__(256) void softmax_bf16(__bf16* __restrict__ S) {
    int row = blockIdx.x * 4 + (threadIdx.x >> 6);
    int lane = threadIdx.x & 63;
    __bf16* p = S + (size_t)row * N_SP + lane * 16;
    bf16x8 v0 = *(bf16x8*)p;
    bf16x8 v1 = *(bf16x8*)(p + 8);
    float f[16];
#pragma unroll
    for (int e = 0; e < 8; ++e) { f[e] = (float)v0[e]; f[8 + e] = (float)v1[e]; }
    float m = f[0];
#pragma unroll
    for (int e = 1; e < 16; ++e) m = fmaxf(m, f[e]);
    for (int off = 32; off > 0; off >>= 1) m = fmaxf(m, __shfl_xor(m, off));
    float s = 0.f;
#pragma unroll
    for (int e = 0; e < 16; ++e) { f[e] = __expf(f[e] - m); s += f[e]; }
    for (int off = 32; off > 0; off >>= 1) s += __shfl_xor(s, off);
    float inv = 1.f / s;
#pragma unroll
    for (int e = 0; e < 8; ++e) { v0[e] = (__bf16)(f[e] * inv); v1[e] = (__bf16)(f[8 + e] * inv); }
    *(bf16x8*)p = v0;
    *(bf16x8*)(p + 8) = v1;
}

// ====== 256x256 8-wave GEMM, m201-style 4-phase K-tiles, depth-2 staging ======
// 8 waves (2M x 4N), wave-tile 128x64, acc[8][4] f32x4. BK=64, LDS 128KB dbuf.
// Per tile t (buf c): P1 {rd aF0-3/bF ks0; BAR; lgk0; prio1; 16 MFMA; prio0; BAR}
// P2 {rd aF4-7 ks0; ...16 MFMA...} P3 {rd aF0-3/bF ks1; ...} P4 {rd aF4-7 ks1;
// lgk0; BAR (buf c free); STG(c, t+2); 16 MFMA; WAITV(8); BAR}. Counted vmcnt:
// entry guarantee = own-slice loads of tile t landed; cross-wave via per-wave
// WAITV + barrier. XOR k-slot swizzle (0 conflicts, verified r3-r10).
// EPI: 0 bf16; 2 bf16+bias[row]; 4 f32+bias[row]+resid; 5 bf16*scale;
//      6 bf16+bias[col] split cols<512 -> Y, >=512 -> Y2 (both ld 512)
#define WAITV(n) asm volatile("s_waitcnt vmcnt(" #n ")" ::: "memory")
#define LGK0()   asm volatile("s_waitcnt lgkmcnt(0)" ::: "memory")
#define BAR() __builtin_amdgcn_s_barrier()

template <int M, int N, int K, int LDA, int LDB, int EPI>
__global__ __launch_bounds__(512, 2) void gemm8(const __bf16* __restrict__ A, size_t sA,
                                                const __bf16* __restrict__ BT, size_t sB,
                                                void* __restrict__ Y, size_t sY,
                                                const float* __restrict__ bias,
                                                const float* __restrict__ resid, size_t sR,
                                                float scale, void* __restrict__ Y2) {
    static_assert(M % 256 == 0 && N % 256 == 0 && K % 128 == 0, "shape");
    constexpr int GX = N / 256, GY = M / 256, NT = K / 64;
    __shared__ __align__(16) __bf16 lds[2][2][16384];  // [buf][A/B][256 rows x 64 k]

    const int tid = threadIdx.x;
    const int w = tid >> 6, lane = tid & 63;
    const int wm = w >> 2, wn = w & 3;                 // 2 x 4 wave grid, tile 128x64
    const int lrow = lane & 15, koct = lane >> 4;

    const int nwg = gridDim.x;
    const int wg = ((int)blockIdx.x & 7) * (nwg >> 3) + ((int)blockIdx.x >> 3);
    const int bz = wg / (GX * GY);
    const int rem = wg - bz * (GX * GY);
    const int bm = (rem / GX) * 256, bn = (rem % GX) * 256;

    const __bf16* Ab = A + (size_t)bz * sA;
    const __bf16* Bb = BT + (size_t)bz * sB;

    // staging: 512 thr cover 64 rows/gload (8 gloads per K-tile); src k pre-swizzled
    const int srow = tid >> 3;                          // 0..63
    const int kswz = ((tid & 7) ^ (srow & 7)) * 8;
    const __bf16* srcA = Ab + (size_t)(bm + srow) * LDA + kswz;
    const __bf16* srcB = Bb + (size_t)(bn + srow) * LDB + kswz;
    __bf16* dA = &lds[0][0][w * 512];                   // wave-uniform bases
    __bf16* dB = &lds[0][1][w * 512];
    constexpr int BUFSTR = 2 * 16384;                   // elems between buf 0 and 1

#define STG(buf, kt) do { \
    gload16(srcA + (size_t)(kt) * 64,                     dA + (buf) * BUFSTR); \
    gload16(srcA + (size_t)64 * LDA + (size_t)(kt) * 64,  dA + (buf) * BUFSTR + 4096); \
    gload16(srcA + (size_t)128 * LDA + (size_t)(kt) * 64, dA + (buf) * BUFSTR + 8192); \
    gload16(srcA + (size_t)192 * LDA + (size_t)(kt) * 64, dA + (buf) * BUFSTR + 12288); \
    gload16(srcB + (size_t)(kt) * 64,                     dB + (buf) * BUFSTR); \
    gload16(srcB + (size_t)64 * LDB + (size_t)(kt) * 64,  dB + (buf) * BUFSTR + 4096); \
    gload16(srcB + (size_t)128 * LDB + (size_t)(kt) * 64, dB + (buf) * BUFSTR + 8192); \
    gload16(srcB + (size_t)192 * LDB + (size_t)(kt) * 64, dB + (buf) * BUFSTR + 12288); \
} while (0)

    // fragment reads (read side of the swizzle involution)
    const int ks0 = (koct ^ (lrow & 7)) * 8;
    const int ks1 = ks0 ^ 32;
    const int abase = (wm * 128 + lrow) * 64;
    const int bbase = (wn * 64 + lrow) * 64;

    bf16x8 aLo[4], aHi[4], bF[4];
    f32x4 acc[8][4];
#pragma unroll
    for (int i = 0; i < 8; ++i)
#pragma unroll
        for (int j = 0; j < 4; ++j) acc[i][j] = (f32x4){0.f, 0.f, 0.f, 0.f};

#define RD_ALO(ct, KS) do { _Pragma("unroll") for (int i = 0; i < 4; ++i) \
    aLo[i] = *(const bf16x8*)&lds[ct][0][abase + i * 1024 + (KS)]; } while (0)
#define RD_AHI(ct, KS) do { _Pragma("unroll") for (int i = 0; i < 4; ++i) \
    aHi[i] = *(const bf16x8*)&lds[ct][0][abase + (i + 4) * 1024 + (KS)]; } while (0)
#define RD_B(ct, KS) do { _Pragma("unroll") for (int j = 0; j < 4; ++j) \
    bF[j] = *(const bf16x8*)&lds[ct][1][bbase + j * 1024 + (KS)]; } while (0)

#define MM16(AF, I0) do { \
    __builtin_amdgcn_s_setprio(1); \
    _Pragma("unroll") for (int i = 0; i < 4; ++i) \
    _Pragma("unroll") for (int j = 0; j < 4; ++j) \
        acc[(I0) + i][j] = __builtin_amdgcn_mfma_f32_16x16x32_bf16( \
            AF[i], bF[j], acc[(I0) + i][j], 0, 0, 0); \
    __builtin_amdgcn_s_setprio(0); \
} while (0)

    // prologue: stage tile 0 and tile 1 (16 gloads in flight), wait tile 0
    STG(0, 0);
    STG(1, 1);
    WAITV(8); BAR();

#pragma unroll 1
    for (int t = 0; t < NT; ++t) {
        const int c = t & 1;
        // P1: aF0-3 ks0, B ks0 -> acc[0..3] k0
        RD_ALO(c, ks0); RD_B(c, ks0);
        BAR(); LGK0();
        MM16(aLo, 0);
        BAR();
        // P2: aF4-7 ks0 -> acc[4..7] k0
        RD_AHI(c, ks0);
        BAR(); LGK0();
        MM16(aHi, 4);
        BAR();
        // P3: aF0-3 ks1, B ks1 -> acc[0..3] k1
        RD_ALO(c, ks1); RD_B(c, ks1);
        BAR(); LGK0();
        MM16(aLo, 0);
        BAR();
        // P4: aF4-7 ks1; free buf c; stage t+2 into it; MFMA covers issue
        RD_AHI(c, ks1);
        LGK0();
        __builtin_amdgcn_sched_barrier(0);
        BAR();                               // all waves done reading buf c
        if (t + 2 < NT) STG(c, t + 2);
        MM16(aHi, 4);
        if (t + 2 < NT)      { WAITV(8); }   // retire tile t+1's 8 loads
        else if (t + 1 < NT) { WAITV(0); }   // last prefetched tile: drain
        BAR();
    }

    // epilogue: C/D layout col=lane&15, row=koct*4+reg
    float* Yf = (float*)Y + (size_t)bz * sY;
    __bf16* Yh = (__bf16*)Y + (size_t)bz * sY;
    const float* Rb = (EPI == 4) ? (resid + (size_t)bz * sR) : nullptr;
    __bf16* Y6 = (EPI == 6) ? ((bn < 512) ? (__bf16*)Y : (__bf16*)Y2) : nullptr;
#pragma unroll
    for (int i = 0; i < 8; ++i)
#pragma unroll
        for (int r = 0; r < 4; ++r) {
            int grow = bm + wm * 128 + i * 16 + koct * 4 + r;
            float brv = (EPI == 2 || EPI == 4) ? bias[grow] : 0.f;
#pragma unroll
            for (int j = 0; j < 4; ++j) {
                int gcol = bn + wn * 64 + j * 16 + lrow;
                float vv = acc[i][j][r];
                if (EPI == 6) vv += bias[gcol];
                if (EPI == 2 || EPI == 4) vv += brv;
                if (EPI == 5) vv *= scale;
                if (EPI == 4) {
                    size_t yi = (size_t)grow * N + gcol;
                    Yf[yi] = vv + Rb[yi];
                } else if (EPI == 6) {
                    Y6[(size_t)grow * 512 + (gcol & 511)] = (__bf16)vv;
                } else {
                    Yh[(size_t)grow * N + gcol] = (__bf16)vv;
                }
            }
        }
#undef STG
#undef RD_ALO
#undef RD_AHI
#undef RD_B
#undef MM16
}

extern "C" void kernel_launch(void* const* d_in, const int* in_sizes, int n_in,
                              void* d_out, int out_size, void* d_ws, size_t ws_size,
                              hipStream_t stream) {
    const float* x      = (const float*)d_in[0];
    const float* norm_w = (const float*)d_in[1];
    const float* norm_b = (const float*)d_in[2];
    const float* q_w    = (const float*)d_in[3];
    const float* q_b    = (const float*)d_in[4];
    const float* k_w    = (const float*)d_in[5];
    const float* k_b    = (const float*)d_in[6];
    const float* v_w    = (const float*)d_in[7];
    const float* v_b    = (const float*)d_in[8];
    const float* proj_w = (const float*)d_in[9];
    const float* proj_b = (const float*)d_in[10];
    float* out = (float*)d_out;

    const size_t ELEM = (size_t)N_SP * C_DIM;            // 524288 elems = 1MB bf16
    const size_t QK   = (size_t)N_SP * N_SP;
    char* ws = (char*)d_ws;
    __bf16* hT  = (__bf16*)ws;                           // 32MB [b][n][c], reused as Ot
    __bf16* qT  = (__bf16*)(ws + ((size_t)32 << 20));    // 32MB [b][n][512]
    __bf16* kT  = (__bf16*)(ws + ((size_t)64 << 20));    // 32MB [b][n][512]
    __bf16* wqk = (__bf16*)(ws + ((size_t)96 << 20));    // 1MB [1024][512]
    __bf16* wv  = (__bf16*)(ws + ((size_t)97 << 20));    // 0.5MB
    __bf16* wp  = wv + 262144;                           // 0.5MB
    float* qkb  = (float*)(ws + ((size_t)98 << 20));     // 4KB
    size_t sbase = ((size_t)99 << 20);
    __bf16* S = (__bf16*)(ws + sbase);                   // chunk x [1024][1024] bf16
    __bf16* v  = (__bf16*)d_out;                         // V lives in d_out until proj
    __bf16* Ot = hT;

    int chunk = (int)((ws_size - sbase) >> 21);          // 2MB per batch of S
    if (chunk > B_DIM) chunk = B_DIM;
    if (chunk < 1) chunk = 1;

    gn_fused_kernel<<<B_DIM * GROUPS, 256, 0, stream>>>(x, norm_w, norm_b, hT);
    prep_kernel<<<1025, 256, 0, stream>>>(q_w, k_w, v_w, proj_w, q_b, k_b,
                                          wqk, wv, wp, qkb);

    // qT[n][oc] / kT[n][oc] = hT[n][:] x (wq||wk)^T + bias, split outputs
    gemm8<32768, 1024, 512, 512, 512, 6><<<512, 512, 0, stream>>>(
        hT, 0, wqk, 0, qT, 0, qkb, nullptr, 0, 1.f, kT);
    // v[b][oc][n] = wv[oc][:] x hT[b][n][:] + v_b[oc]
    gemm8<512, 1024, 512, 512, 512, 2><<<256, 512, 0, stream>>>(
        wv, 0, hT, ELEM, v, ELEM, v_b, nullptr, 0, 1.f, nullptr);

    const float scale = 0.044194173824159216f;  // 512^-0.5
    for (int b0 = 0; b0 < B_DIM; b0 += chunk) {
        int nb = (b0 + chunk <= B_DIM) ? chunk : (B_DIM - b0);
        // S[i][j] = bf16( scale * sum_c qT[i][c] kT[j][c] )
        gemm8<1024, 1024, 512, 512, 512, 5><<<16 * nb, 512, 0, stream>>>(
            qT + (size_t)b0 * ELEM, ELEM, kT + (size_t)b0 * ELEM, ELEM,
            S, QK, nullptr, nullptr, 0, scale, nullptr);
        softmax_bf16<<<nb * N_SP / 4, 256, 0, stream>>>(S);
        // Ot[i][c] = sum_j P[i][j] v[c][j]
        gemm8<1024, 512, 1024, 1024, 1024, 0><<<8 * nb, 512, 0, stream>>>(
            S, QK, v + (size_t)b0 * ELEM, ELEM,
            Ot + (size_t)b0 * ELEM, ELEM, nullptr, nullptr, 0, 1.f, nullptr);
    }

    // out[b][oc][n] = wp[oc][:] x Ot[b][n][:] + proj_b[oc] + x[b][oc][n]
    gemm8<512, 1024, 512, 512, 512, 4><<<256, 512, 0, stream>>>(
        wp, 0, Ot, ELEM, out, ELEM, proj_b, x, ELEM, 1.f, nullptr);
}